// Round 10
// baseline (211.377 us; speedup 1.0000x reference)
//
#include <hip/hip_runtime.h>
#include <cstddef>

#define Bn 128
#define Pn 8732
#define Cn 21
#define On 16
#define MAGIC 0x13579BDFu

#define SB() __builtin_amdgcn_sched_barrier(0)
#define VW(n) asm volatile("s_waitcnt vmcnt(" #n ")" ::: "memory")
#define USE4(v) asm volatile("" :: "v"((v).x), "v"((v).y), "v"((v).z), "v"((v).w))

__device__ __forceinline__ void argmax_combine(float& v, int& p, float v2, int p2) {
  if (v2 > v || (v2 == v && p2 < p)) { v = v2; p = p2; }
}

__device__ __forceinline__ float sl1_enc(float4 lv, float4 d,
                                         float t0, float t1, float t2, float t3) {
  float g0 = ((t0 + t2) * 0.5f - d.x) / (0.1f * d.z);
  float g1 = ((t1 + t3) * 0.5f - d.y) / (0.1f * d.w);
  float g2 = __logf((t2 - t0) / d.z) / 0.2f;
  float g3 = __logf((t3 - t1) / d.w) / 0.2f;
  float r = 0.f, a;
  a = fabsf(lv.x - g0); r += (a < 1.f) ? 0.5f * a * a : a - 0.5f;
  a = fabsf(lv.y - g1); r += (a < 1.f) ? 0.5f * a * a : a - 0.5f;
  a = fabsf(lv.z - g2); r += (a < 1.f) ? 0.5f * a * a : a - 0.5f;
  a = fabsf(lv.w - g3); r += (a < 1.f) ? 0.5f * a * a : a - 0.5f;
  return r;
}

// ---------------------------------------------------------------------------
// Kernel A: 1-wave blocks (4096 x 64), global_load_lds double-buffered chunk
// pipeline. Per chunk: 6 HBM->LDS DMA instrs (no VGPR round-trip), counted
// vmcnt waits (8 = 2 stores + 6 next-chunk loads in flight) so the next
// chunk's loads overlap this chunk's softmax+IoU. All other loop VMEM (dbox)
// hoisted to prologue and reg-forced so the compiler never drains the queue.
// Work mapping identical to the 62us round-2 kernel.
// ---------------------------------------------------------------------------
__global__ __launch_bounds__(64) void stream_kernel(
    const float* __restrict__ conf, const float* __restrict__ dbox,
    const float* __restrict__ targets,
    float* __restrict__ ce0, unsigned char* __restrict__ pack,
    unsigned long long* __restrict__ keys) {
  const int lane = threadIdx.x;
  const int b = blockIdx.x & 127;
  const int cg = blockIdx.x >> 7;                // 0..31

  __shared__ float4 s_buf[2][336];               // double buffer, 10752 B
  __shared__ float s_tt[On * 5];
  __shared__ float s_ar[On];

  // ---- targets staging (80 > 64 lanes: strided) ----
  const size_t tb = (size_t)b * On * 5;
  for (int i = lane; i < On * 5; i += 64) s_tt[i] = targets[tb + i];
  if (lane < On) {
    float x1 = targets[tb + lane * 5 + 0];
    float y1 = targets[tb + lane * 5 + 1];
    float x2 = targets[tb + lane * 5 + 2];
    float y2 = targets[tb + lane * 5 + 3];
    s_ar[lane] = (x2 - x1) * (y2 - y1);
  }

  // ---- chunk geometry: c_i = cg + 32*i; c0..c3 always valid; c4 iff cg<9 ----
  const int c0 = cg, c1 = cg + 32, c2 = cg + 64, c3 = cg + 96, c4 = cg + 128;
  const bool has5 = (cg < 9);
  const bool full5 = (cg < 8);                   // cg==8 -> chunk 136 partial

  // ---- dbox prefetch for all my chunks (prologue; reg-forced) ----
  float4 d0 = ((const float4*)dbox)[c0 * 64 + lane];
  float4 d1 = ((const float4*)dbox)[c1 * 64 + lane];
  float4 d2 = ((const float4*)dbox)[c2 * 64 + lane];
  float4 d3 = ((const float4*)dbox)[c3 * 64 + lane];
  float4 d4 = make_float4(0.f, 0.f, 0.f, 0.f);
  if (has5 && (c4 * 64 + lane) < Pn) d4 = ((const float4*)dbox)[c4 * 64 + lane];
  USE4(d0); USE4(d1); USE4(d2); USE4(d3); USE4(d4);  // force waits HERE

  float bestv[On]; int bestp[On];
  #pragma unroll
  for (int j = 0; j < On; j++) { bestv[j] = -1.0f; bestp[j] = 0x7fffffff; }

  auto STAGE = [&](int bi, int ci) {
    const int p0 = ci * 64;
    const int n4 = min(64, Pn - p0) * Cn / 4;    // 336 (6 instrs) or 147 (3)
    const float4* src = (const float4*)(conf + ((size_t)b * Pn + p0) * Cn);
    #pragma unroll
    for (int k = 0; k < 6; k++) {
      if (64 * k + lane < n4) {
        __builtin_amdgcn_global_load_lds(
            (const __attribute__((address_space(1))) unsigned int*)(src + 64 * k + lane),
            (__attribute__((address_space(3))) unsigned int*)(&s_buf[bi][64 * k]),
            16, 0, 0);
      }
    }
  };

  auto COMPUTE = [&](int ci, int bi, float4 d) {
    const int p0 = ci * 64;
    const int rows = min(64, Pn - p0);
    if (lane < rows) {
      const int p = p0 + lane;
      const float* x = (const float*)s_buf[bi] + lane * Cn;  // 2-way bank: free
      float m = x[0];
      #pragma unroll
      for (int q = 1; q < Cn; q++) m = fmaxf(m, x[q]);
      float s = 0.0f;
      #pragma unroll
      for (int q = 0; q < Cn; q++) s += __expf(x[q] - m);
      float lse = m + __logf(s);
      ce0[(size_t)b * Pn + p] = lse - x[0];

      float px1 = d.x - d.z * 0.5f, py1 = d.y - d.w * 0.5f;
      float px2 = d.x + d.z * 0.5f, py2 = d.y + d.w * 0.5f;
      float ap = d.z * d.w;
      float mv = -1.0f; int mj = 0;
      #pragma unroll
      for (int j = 0; j < On; j++) {
        float lx = fmaxf(s_tt[j*5+0], px1);
        float ly = fmaxf(s_tt[j*5+1], py1);
        float rx = fminf(s_tt[j*5+2], px2);
        float ry = fminf(s_tt[j*5+3], py2);
        float w = fmaxf(rx - lx, 0.0f), h = fmaxf(ry - ly, 0.0f);
        float inter = w * h;
        float ov = __fdividef(inter, s_ar[j] + ap - inter);
        if (ov > bestv[j]) { bestv[j] = ov; bestp[j] = p; }  // smallest p kept
        if (ov > mv) { mv = ov; mj = j; }                    // first max over j
      }
      pack[(size_t)b * Pn + p] =
          (unsigned char)(mj | ((mv >= 0.5f) ? 16 : 0));
    }
  };

  // ---- software pipeline: stage(next) || compute(cur), counted vmcnt ----
  VW(0); SB();                       // clean queue after prologue
  STAGE(0, c0); SB();
  STAGE(1, c1); SB(); VW(6); SB();   // buf0 done; buf1 (6) in flight
  COMPUTE(c0, 0, d0); SB();
  STAGE(0, c2); SB(); VW(8); SB();   // buf1 done; 2 stores + buf0(6) in flight
  COMPUTE(c1, 1, d1); SB();
  STAGE(1, c3); SB(); VW(8); SB();
  COMPUTE(c2, 0, d2); SB();
  if (has5) {
    STAGE(0, c4); SB();
    if (full5) { VW(8); } else { VW(5); }  // partial chunk 136 issues 3, not 6
    SB();
    COMPUTE(c3, 1, d3); SB();
    VW(0); SB();                     // drain tail
    COMPUTE(c4, 0, d4);
  } else {
    VW(0); SB();
    COMPUTE(c3, 1, d3);
  }

  // per-truth argmax: wave shuffle reduce, then device atomicMax
  #pragma unroll
  for (int j = 0; j < On; j++) {
    float v = bestv[j]; int p = bestp[j];
    #pragma unroll
    for (int off = 32; off; off >>= 1) {
      float v2 = __shfl_down(v, off);
      int p2 = __shfl_down(p, off);
      argmax_combine(v, p, v2, p2);
    }
    if (lane == 0) {
      unsigned long long key;
      if (v < 0.0f) key = 0xC000000000000000ull;   // neutral, still beats poison
      else key = (((unsigned long long)(__float_as_uint(v) | 0xC0000000u)) << 32)
               | (unsigned long long)(0xFFFFFFFFu - (unsigned)p);
      atomicMax(&keys[b * On + j], key);
    }
  }
}

// ---------------------------------------------------------------------------
// Kernel B: unchanged from round 9 (bitmap forced-match handling, radix
// top-k, MAGIC finalize).
// ---------------------------------------------------------------------------
__global__ __launch_bounds__(1024) void reduce_kernel(
    const float* __restrict__ loc, const float* __restrict__ conf,
    const float* __restrict__ dbox, const float* __restrict__ targets,
    const float* __restrict__ ce0, const unsigned char* __restrict__ pack,
    const unsigned long long* __restrict__ keys,
    unsigned int* __restrict__ res, float* __restrict__ out) {
  const int b = blockIdx.x;
  const int tid = threadIdx.x;
  const int wave = tid >> 6, lane = tid & 63;

  __shared__ float s_t[On * 5];
  __shared__ int s_bp[On];
  __shared__ unsigned s_bm[273];            // prior bitmap: 273*32 >= 8732
  __shared__ unsigned hist[256 * 16];       // [bin][wave], 16 KB
  __shared__ unsigned s_col[256];
  __shared__ unsigned s_cand[64];
  __shared__ float s_redf[2][16];
  __shared__ int s_redi[16];
  __shared__ unsigned s_prefix;
  __shared__ int s_kk;
  __shared__ int s_cnt;
  __shared__ int s_cc;
  __shared__ int s_np;
  __shared__ float s_floc, s_fcep;

  if (tid < On * 5) s_t[tid] = targets[(size_t)b * On * 5 + tid];
  if (tid < 273) s_bm[tid] = 0;
  __syncthreads();
  if (tid < On) {
    int bp = (int)(0xFFFFFFFFu - (unsigned)(keys[b * On + tid] & 0xFFFFFFFFull));
    s_bp[tid] = bp;
    atomicOr(&s_bm[bp >> 5], 1u << (bp & 31));
  }
  __syncthreads();

  // ---- wave 0, lanes 0-15: losses for the <=16 forced priors ----
  if (wave == 0) {
    float f_loc = 0.f, f_cep = 0.f;
    const bool valid = lane < On;
    const int p = valid ? s_bp[lane] : 0;
    bool dup = false;
    if (valid)
      for (int j2 = lane + 1; j2 < On; j2++) dup |= (s_bp[j2] == p);
    if (valid && !dup) {                     // last j wins on collisions
      const float* row = conf + ((size_t)b * Pn + p) * Cn;
      float m = row[0];
      #pragma unroll
      for (int q = 1; q < Cn; q++) m = fmaxf(m, row[q]);
      float s = 0.f;
      #pragma unroll
      for (int q = 0; q < Cn; q++) s += __expf(row[q] - m);
      const float lse = m + __logf(s);
      const int c = (int)s_t[lane * 5 + 4] + 1;
      f_cep = lse - row[c];                  // global read: no runtime reg-idx
      const float4 d = ((const float4*)dbox)[p];
      const float4 lv = ((const float4*)loc)[(size_t)b * Pn + p];
      f_loc = sl1_enc(lv, d, s_t[lane*5+0], s_t[lane*5+1],
                             s_t[lane*5+2], s_t[lane*5+3]);
    }
    #pragma unroll
    for (int off = 32; off; off >>= 1) {
      f_loc += __shfl_down(f_loc, off);
      f_cep += __shfl_down(f_cep, off);
    }
    if (lane == 0) { s_floc = f_loc; s_fcep = f_cep; }
  }

  // ---- bulk data pass (bitmap test instead of 16 compares) ----
  float ce_r[9];
  float my_loc = 0.0f, my_cep = 0.0f; int my_np = 0;
  #pragma unroll
  for (int sI = 0; sI < 9; sI++) {
    ce_r[sI] = 0.0f;
    const int p = tid + 1024 * sI;
    if (p < Pn) {
      unsigned char pk = pack[(size_t)b * Pn + p];
      float c0 = ce0[(size_t)b * Pn + p];
      const unsigned forced = (s_bm[p >> 5] >> (p & 31)) & 1u;
      const int posb = (pk >> 4);
      const int pos = posb | (int)forced;
      ce_r[sI] = pos ? 0.0f : c0;
      if (pos) my_np++;                      // forced counted once here
      if (posb && !forced) {                 // forced losses handled by wave 0
        const int bt = pk & 15;
        const float* t = &s_t[bt * 5];
        int c = (int)t[4] + 1;
        const float* row = conf + ((size_t)b * Pn + p) * Cn;
        my_cep += c0 + row[0] - row[c];      // lse - x[c]
        float4 d = ((const float4*)dbox)[p];
        float4 ld = ((const float4*)loc)[(size_t)b * Pn + p];
        my_loc += sl1_enc(ld, d, t[0], t[1], t[2], t[3]);
      }
    }
  }

  {
    int np = my_np;
    #pragma unroll
    for (int off = 32; off; off >>= 1) np += __shfl_down(np, off);
    if (lane == 0) s_redi[wave] = np;
  }
  __syncthreads();
  if (tid == 0) {
    int np = 0;
    #pragma unroll
    for (int w = 0; w < 16; w++) np += s_redi[w];
    s_np = np;
  }
  __syncthreads();

  // ---- exact k-th largest over register ce_neg values (all >= 0) ----
  const int k = min(s_np * 3, Pn);
  unsigned prefix = 0, maskb = 0;
  int kk = k;
  int cntc = Pn;
  for (int shift = 24; shift >= 0; shift -= 8) {
    if (cntc <= 64) break;                         // small-select path below
    ((uint4*)hist)[tid] = make_uint4(0u, 0u, 0u, 0u);
    __syncthreads();
    #pragma unroll
    for (int sI = 0; sI < 9; sI++) {
      const int p = tid + 1024 * sI;
      if (p < Pn) {
        unsigned u = __float_as_uint(ce_r[sI]);
        if ((u & maskb) == prefix)
          atomicAdd(&hist[(((u >> shift) & 255u) << 4) + (unsigned)wave], 1u);
      }
    }
    __syncthreads();
    if (tid < 256) {
      unsigned c = 0;
      #pragma unroll
      for (int w = 0; w < 16; w++) c += hist[(tid << 4) + w];
      s_col[tid] = c;
    }
    __syncthreads();
    if (tid < 64) {
      // wave-0 parallel suffix scan over 256 bins (4 per lane)
      unsigned c0 = s_col[4 * tid + 0], c1 = s_col[4 * tid + 1];
      unsigned c2 = s_col[4 * tid + 2], c3 = s_col[4 * tid + 3];
      unsigned t0 = c0 + c1 + c2 + c3;
      unsigned S = t0;
      #pragma unroll
      for (int off = 1; off < 64; off <<= 1) {
        unsigned o = __shfl_down(S, off);
        if (tid + off < 64) S += o;
      }
      unsigned Snext = S - t0;                     // suffix of lanes > tid
      unsigned s3 = Snext + c3;
      unsigned s2 = s3 + c2;
      unsigned s1 = s2 + c1;
      unsigned s0 = s1 + c0;
      unsigned kk_u = (unsigned)kk;
      int chosen = -1; unsigned snx = 0, cc = 0;
      if (s3 >= kk_u && Snext < kk_u)      { chosen = 3; snx = Snext; cc = c3; }
      else if (s2 >= kk_u && s3 < kk_u)    { chosen = 2; snx = s3;    cc = c2; }
      else if (s1 >= kk_u && s2 < kk_u)    { chosen = 1; snx = s2;    cc = c1; }
      else if (s0 >= kk_u && s1 < kk_u)    { chosen = 0; snx = s1;    cc = c0; }
      if (chosen >= 0) {                           // exactly one lane hits
        s_prefix = prefix | ((unsigned)(4 * tid + chosen) << shift);
        s_kk = (int)(kk_u - snx);
        s_cnt = (int)cc;
      }
    }
    __syncthreads();
    prefix = s_prefix; kk = s_kk; cntc = s_cnt;
    maskb |= 255u << shift;
  }
  if (maskb != 0xFFFFFFFFu) {
    // <= 64 candidates share the prefix: exact rank-select in one wave
    if (tid == 0) s_cc = 0;
    __syncthreads();
    #pragma unroll
    for (int sI = 0; sI < 9; sI++) {
      const int p = tid + 1024 * sI;
      if (p < Pn) {
        unsigned u = __float_as_uint(ce_r[sI]);
        if ((u & maskb) == prefix) {
          int ix = atomicAdd(&s_cc, 1);
          if (ix < 64) s_cand[ix] = u;
        }
      }
    }
    __syncthreads();
    if (tid < 64) {
      int c = min(s_cc, 64);
      if (tid < c) {
        unsigned v = s_cand[tid];
        int g = 0, e = 0;
        for (int i = 0; i < c; i++) {
          unsigned w = s_cand[i];
          g += (w > v); e += (w == v);
        }
        if (g < kk && kk <= g + e) s_prefix = v;   // tie-safe: all writers equal
      }
    }
    __syncthreads();
    prefix = s_prefix;
  }
  float T = __uint_as_float(prefix);

  float sum_gt = 0.0f; int cnt_gt = 0;
  #pragma unroll
  for (int sI = 0; sI < 9; sI++) {
    const int p = tid + 1024 * sI;
    if (p < Pn) {
      float x = ce_r[sI];
      if (x > T) { sum_gt += x; cnt_gt++; }
    }
  }
  #pragma unroll
  for (int off = 32; off; off >>= 1) {
    sum_gt += __shfl_down(sum_gt, off);
    cnt_gt += __shfl_down(cnt_gt, off);
    my_loc += __shfl_down(my_loc, off);
    my_cep += __shfl_down(my_cep, off);
  }
  if (lane == 0) {
    s_redf[0][wave] = my_loc; s_redf[1][wave] = sum_gt + my_cep; s_redi[wave] = cnt_gt;
  }
  __syncthreads();
  if (tid == 0) {
    float ll = s_floc, lc = s_fcep; int cg2 = 0;
    #pragma unroll
    for (int w = 0; w < 16; w++) {
      ll += s_redf[0][w]; lc += s_redf[1][w]; cg2 += s_redi[w];
    }
    lc += (k > 0) ? (float)(k - cg2) * T : 0.0f;
    // post partials (device-scope atomics; visible cross-XCD), then flag
    atomicExch(&res[b * 4 + 0], __float_as_uint(ll));
    atomicExch(&res[b * 4 + 1], __float_as_uint(lc));
    atomicExch(&res[b * 4 + 2], (unsigned)s_np);
    __threadfence();
    atomicExch(&res[b * 4 + 3], MAGIC);
  }

  // block 0, wave 0: gather all 128 partials and finalize (no extra kernel)
  if (b == 0 && tid < 64) {
    float ll = 0.0f, lc = 0.0f; int np = 0;
    #pragma unroll
    for (int h = 0; h < 2; h++) {
      const int i = tid + 64 * h;
      while (atomicAdd(&res[i * 4 + 3], 0u) != MAGIC) { __builtin_amdgcn_s_sleep(8); }
      ll += __uint_as_float(atomicAdd(&res[i * 4 + 0], 0u));
      lc += __uint_as_float(atomicAdd(&res[i * 4 + 1], 0u));
      np += (int)atomicAdd(&res[i * 4 + 2], 0u);
    }
    #pragma unroll
    for (int off = 32; off; off >>= 1) {
      ll += __shfl_down(ll, off);
      lc += __shfl_down(lc, off);
      np += __shfl_down(np, off);
    }
    if (tid == 0) {
      float fN = (float)np;
      out[0] = ll / fN;
      out[1] = lc / fN;
    }
  }
}

extern "C" void kernel_launch(void* const* d_in, const int* in_sizes, int n_in,
                              void* d_out, int out_size, void* d_ws, size_t ws_size,
                              hipStream_t stream) {
  const float* loc_data  = (const float*)d_in[0];
  const float* conf_data = (const float*)d_in[1];
  const float* dbox      = (const float*)d_in[2];
  const float* targets   = (const float*)d_in[3];
  float* out = (float*)d_out;

  char* ws = (char*)d_ws;
  float* ce0 = (float*)ws;                                           // B*P f32
  unsigned char* pack = (unsigned char*)(ws + (size_t)Bn * Pn * 4);  // B*P bytes
  unsigned long long* keys =
      (unsigned long long*)(ws + (size_t)Bn * Pn * 5);               // B*16 u64
  unsigned int* res = (unsigned int*)(ws + (size_t)Bn * Pn * 5 + Bn * On * 8); // B*4 u32

  stream_kernel<<<4096, 64, 0, stream>>>(conf_data, dbox, targets, ce0, pack, keys);
  reduce_kernel<<<Bn, 1024, 0, stream>>>(loc_data, conf_data, dbox, targets,
                                         ce0, pack, keys, res, out);
}

// Round 11
// 200.266 us; speedup vs baseline: 1.0555x; 1.0555x over previous
//
#include <hip/hip_runtime.h>
#include <cstddef>

#define Bn 128
#define Pn 8732
#define Cn 21
#define On 16
#define MAGIC 0x13579BDFu

__device__ __forceinline__ void argmax_combine(float& v, int& p, float v2, int p2) {
  if (v2 > v || (v2 == v && p2 < p)) { v = v2; p = p2; }
}

__device__ __forceinline__ float sl1_enc(float4 lv, float4 d,
                                         float t0, float t1, float t2, float t3) {
  float g0 = ((t0 + t2) * 0.5f - d.x) / (0.1f * d.z);
  float g1 = ((t1 + t3) * 0.5f - d.y) / (0.1f * d.w);
  float g2 = __logf((t2 - t0) / d.z) / 0.2f;
  float g3 = __logf((t3 - t1) / d.w) / 0.2f;
  float r = 0.f, a;
  a = fabsf(lv.x - g0); r += (a < 1.f) ? 0.5f * a * a : a - 0.5f;
  a = fabsf(lv.y - g1); r += (a < 1.f) ? 0.5f * a * a : a - 0.5f;
  a = fabsf(lv.z - g2); r += (a < 1.f) ? 0.5f * a * a : a - 0.5f;
  a = fabsf(lv.w - g3); r += (a < 1.f) ? 0.5f * a * a : a - 0.5f;
  return r;
}

// ---------------------------------------------------------------------------
// Kernel A: round-2/9 structure (57.6 us best measured) with ONE change:
// dependency-chain re-association in the per-prior compute.
//   - max over 21: 20-deep fmax chain -> max3-shaped tree (depth ~3)
//   - exp-sum: 21-deep serial add -> 4 parallel accumulators (depth ~6)
//   - best-truth argmax: 16-deep select chain -> 2 x 8-deep + combine
// Latency-bound regime (HBM 12%, VALU 40%, occ 35%): shorter chains cut
// per-wave serial time directly. Everything else byte-identical to R9.
// ---------------------------------------------------------------------------
__global__ __launch_bounds__(256) void stream_kernel(
    const float* __restrict__ conf, const float* __restrict__ dbox,
    const float* __restrict__ targets,
    float* __restrict__ ce0, unsigned char* __restrict__ pack,
    unsigned long long* __restrict__ keys) {
  const int wb = threadIdx.x >> 6, lane = threadIdx.x & 63;
  const int wave_g = blockIdx.x * 4 + wb;
  const int b = wave_g & 127;
  const int cg = wave_g >> 7;                    // 0..31

  __shared__ float4 s_row4[4][336];              // 5376 B per wave
  __shared__ float s_tt[4][On * 5];
  __shared__ float s_ar[4][On];

  // On*5 = 80 > 64 lanes: strided fill covers elements 64..79 (truths 12-15).
  for (int i = lane; i < On * 5; i += 64)
    s_tt[wb][i] = targets[(size_t)b * On * 5 + i];
  if (lane < On) {
    float x1 = targets[(size_t)b * On * 5 + lane * 5 + 0];
    float y1 = targets[(size_t)b * On * 5 + lane * 5 + 1];
    float x2 = targets[(size_t)b * On * 5 + lane * 5 + 2];
    float y2 = targets[(size_t)b * On * 5 + lane * 5 + 3];
    s_ar[wb][lane] = (x2 - x1) * (y2 - y1);
  }

  float bestv[On]; int bestp[On];
  #pragma unroll
  for (int j = 0; j < On; j++) { bestv[j] = -1.0f; bestp[j] = 0x7fffffff; }

  #pragma unroll
  for (int i = 0; i < 5; i++) {
    const int ci = cg + 32 * i;
    if (ci >= 137) break;
    const int p0 = ci * 64;
    const int rows = min(64, Pn - p0);           // 64 or 28 (both %4==0)
    const int n4 = rows * Cn / 4;                // 336 or 147

    const float4* src = (const float4*)(conf + ((size_t)b * Pn + p0) * Cn);
    float4 v0, v1, v2, v3, v4, v5;
    if (lane < n4)        v0 = src[lane];
    if (lane + 64 < n4)   v1 = src[lane + 64];
    if (lane + 128 < n4)  v2 = src[lane + 128];
    if (lane + 192 < n4)  v3 = src[lane + 192];
    if (lane + 256 < n4)  v4 = src[lane + 256];
    if (lane + 320 < n4)  v5 = src[lane + 320];
    if (lane < n4)        s_row4[wb][lane] = v0;
    if (lane + 64 < n4)   s_row4[wb][lane + 64] = v1;
    if (lane + 128 < n4)  s_row4[wb][lane + 128] = v2;
    if (lane + 192 < n4)  s_row4[wb][lane + 192] = v3;
    if (lane + 256 < n4)  s_row4[wb][lane + 256] = v4;
    if (lane + 320 < n4)  s_row4[wb][lane + 320] = v5;

    if (lane < rows) {
      const int p = p0 + lane;
      const float* x = (const float*)s_row4[wb] + lane * Cn;  // stride 21: conflict-free
      // ---- max: max3-shaped tree (depth ~3 v_max3) ----
      float g0 = fmaxf(fmaxf(x[0],  x[1]),  x[2]);
      float g1 = fmaxf(fmaxf(x[3],  x[4]),  x[5]);
      float g2 = fmaxf(fmaxf(x[6],  x[7]),  x[8]);
      float g3 = fmaxf(fmaxf(x[9],  x[10]), x[11]);
      float g4 = fmaxf(fmaxf(x[12], x[13]), x[14]);
      float g5 = fmaxf(fmaxf(x[15], x[16]), x[17]);
      float g6 = fmaxf(fmaxf(x[18], x[19]), x[20]);
      float ha = fmaxf(fmaxf(g0, g1), g2);
      float hb = fmaxf(fmaxf(g3, g4), g5);
      float m  = fmaxf(fmaxf(ha, hb), g6);
      // ---- exp-sum: 4 parallel accumulators (depth ~6 adds) ----
      float s0 = __expf(x[0] - m), s1 = __expf(x[1] - m);
      float s2 = __expf(x[2] - m), s3 = __expf(x[3] - m);
      #pragma unroll
      for (int q = 4; q < 20; q += 4) {
        s0 += __expf(x[q]     - m);
        s1 += __expf(x[q + 1] - m);
        s2 += __expf(x[q + 2] - m);
        s3 += __expf(x[q + 3] - m);
      }
      s0 += __expf(x[20] - m);
      float s = (s0 + s1) + (s2 + s3);
      float lse = m + __logf(s);
      ce0[(size_t)b * Pn + p] = lse - x[0];

      float4 d = ((const float4*)dbox)[p];
      float px1 = d.x - d.z * 0.5f, py1 = d.y - d.w * 0.5f;
      float px2 = d.x + d.z * 0.5f, py2 = d.y + d.w * 0.5f;
      float ap = d.z * d.w;
      // ---- best-truth argmax: two 8-deep halves + combine ----
      float mv0 = -1.0f, mv1 = -1.0f; int mj0 = 0, mj1 = 8;
      #pragma unroll
      for (int j = 0; j < 8; j++) {
        float lx = fmaxf(s_tt[wb][j*5+0], px1);
        float ly = fmaxf(s_tt[wb][j*5+1], py1);
        float rx = fminf(s_tt[wb][j*5+2], px2);
        float ry = fminf(s_tt[wb][j*5+3], py2);
        float w = fmaxf(rx - lx, 0.0f), h = fmaxf(ry - ly, 0.0f);
        float inter = w * h;
        float ov = __fdividef(inter, s_ar[wb][j] + ap - inter);
        if (ov > bestv[j]) { bestv[j] = ov; bestp[j] = p; }  // smallest p kept
        if (ov > mv0) { mv0 = ov; mj0 = j; }                 // first max, low half
      }
      #pragma unroll
      for (int j = 8; j < On; j++) {
        float lx = fmaxf(s_tt[wb][j*5+0], px1);
        float ly = fmaxf(s_tt[wb][j*5+1], py1);
        float rx = fminf(s_tt[wb][j*5+2], px2);
        float ry = fminf(s_tt[wb][j*5+3], py2);
        float w = fmaxf(rx - lx, 0.0f), h = fmaxf(ry - ly, 0.0f);
        float inter = w * h;
        float ov = __fdividef(inter, s_ar[wb][j] + ap - inter);
        if (ov > bestv[j]) { bestv[j] = ov; bestp[j] = p; }
        if (ov > mv1) { mv1 = ov; mj1 = j; }                 // first max, high half
      }
      // tie -> low half (smaller j), matching the original first-max loop
      float mv; int mj;
      if (mv1 > mv0) { mv = mv1; mj = mj1; } else { mv = mv0; mj = mj0; }
      pack[(size_t)b * Pn + p] =
          (unsigned char)(mj | ((mv >= 0.5f) ? 16 : 0));
    }
  }

  // per-truth argmax: wave shuffle reduce, then device atomicMax
  #pragma unroll
  for (int j = 0; j < On; j++) {
    float v = bestv[j]; int p = bestp[j];
    #pragma unroll
    for (int off = 32; off; off >>= 1) {
      float v2 = __shfl_down(v, off);
      int p2 = __shfl_down(p, off);
      argmax_combine(v, p, v2, p2);
    }
    if (lane == 0) {
      unsigned long long key;
      if (v < 0.0f) key = 0xC000000000000000ull;   // neutral, still beats poison
      else key = (((unsigned long long)(__float_as_uint(v) | 0xC0000000u)) << 32)
               | (unsigned long long)(0xFFFFFFFFu - (unsigned)p);
      atomicMax(&keys[b * On + j], key);
    }
  }
}

// ---------------------------------------------------------------------------
// Kernel B: unchanged from round 9 (bitmap forced-match handling, radix
// top-k, MAGIC finalize).
// ---------------------------------------------------------------------------
__global__ __launch_bounds__(1024) void reduce_kernel(
    const float* __restrict__ loc, const float* __restrict__ conf,
    const float* __restrict__ dbox, const float* __restrict__ targets,
    const float* __restrict__ ce0, const unsigned char* __restrict__ pack,
    const unsigned long long* __restrict__ keys,
    unsigned int* __restrict__ res, float* __restrict__ out) {
  const int b = blockIdx.x;
  const int tid = threadIdx.x;
  const int wave = tid >> 6, lane = tid & 63;

  __shared__ float s_t[On * 5];
  __shared__ int s_bp[On];
  __shared__ unsigned s_bm[273];            // prior bitmap: 273*32 >= 8732
  __shared__ unsigned hist[256 * 16];       // [bin][wave], 16 KB
  __shared__ unsigned s_col[256];
  __shared__ unsigned s_cand[64];
  __shared__ float s_redf[2][16];
  __shared__ int s_redi[16];
  __shared__ unsigned s_prefix;
  __shared__ int s_kk;
  __shared__ int s_cnt;
  __shared__ int s_cc;
  __shared__ int s_np;
  __shared__ float s_floc, s_fcep;

  if (tid < On * 5) s_t[tid] = targets[(size_t)b * On * 5 + tid];
  if (tid < 273) s_bm[tid] = 0;
  __syncthreads();
  if (tid < On) {
    int bp = (int)(0xFFFFFFFFu - (unsigned)(keys[b * On + tid] & 0xFFFFFFFFull));
    s_bp[tid] = bp;
    atomicOr(&s_bm[bp >> 5], 1u << (bp & 31));
  }
  __syncthreads();

  // ---- wave 0, lanes 0-15: losses for the <=16 forced priors ----
  if (wave == 0) {
    float f_loc = 0.f, f_cep = 0.f;
    const bool valid = lane < On;
    const int p = valid ? s_bp[lane] : 0;
    bool dup = false;
    if (valid)
      for (int j2 = lane + 1; j2 < On; j2++) dup |= (s_bp[j2] == p);
    if (valid && !dup) {                     // last j wins on collisions
      const float* row = conf + ((size_t)b * Pn + p) * Cn;
      float m = row[0];
      #pragma unroll
      for (int q = 1; q < Cn; q++) m = fmaxf(m, row[q]);
      float s = 0.f;
      #pragma unroll
      for (int q = 0; q < Cn; q++) s += __expf(row[q] - m);
      const float lse = m + __logf(s);
      const int c = (int)s_t[lane * 5 + 4] + 1;
      f_cep = lse - row[c];                  // global read: no runtime reg-idx
      const float4 d = ((const float4*)dbox)[p];
      const float4 lv = ((const float4*)loc)[(size_t)b * Pn + p];
      f_loc = sl1_enc(lv, d, s_t[lane*5+0], s_t[lane*5+1],
                             s_t[lane*5+2], s_t[lane*5+3]);
    }
    #pragma unroll
    for (int off = 32; off; off >>= 1) {
      f_loc += __shfl_down(f_loc, off);
      f_cep += __shfl_down(f_cep, off);
    }
    if (lane == 0) { s_floc = f_loc; s_fcep = f_cep; }
  }

  // ---- bulk data pass (bitmap test instead of 16 compares) ----
  float ce_r[9];
  float my_loc = 0.0f, my_cep = 0.0f; int my_np = 0;
  #pragma unroll
  for (int sI = 0; sI < 9; sI++) {
    ce_r[sI] = 0.0f;
    const int p = tid + 1024 * sI;
    if (p < Pn) {
      unsigned char pk = pack[(size_t)b * Pn + p];
      float c0 = ce0[(size_t)b * Pn + p];
      const unsigned forced = (s_bm[p >> 5] >> (p & 31)) & 1u;
      const int posb = (pk >> 4);
      const int pos = posb | (int)forced;
      ce_r[sI] = pos ? 0.0f : c0;
      if (pos) my_np++;                      // forced counted once here
      if (posb && !forced) {                 // forced losses handled by wave 0
        const int bt = pk & 15;
        const float* t = &s_t[bt * 5];
        int c = (int)t[4] + 1;
        const float* row = conf + ((size_t)b * Pn + p) * Cn;
        my_cep += c0 + row[0] - row[c];      // lse - x[c]
        float4 d = ((const float4*)dbox)[p];
        float4 ld = ((const float4*)loc)[(size_t)b * Pn + p];
        my_loc += sl1_enc(ld, d, t[0], t[1], t[2], t[3]);
      }
    }
  }

  {
    int np = my_np;
    #pragma unroll
    for (int off = 32; off; off >>= 1) np += __shfl_down(np, off);
    if (lane == 0) s_redi[wave] = np;
  }
  __syncthreads();
  if (tid == 0) {
    int np = 0;
    #pragma unroll
    for (int w = 0; w < 16; w++) np += s_redi[w];
    s_np = np;
  }
  __syncthreads();

  // ---- exact k-th largest over register ce_neg values (all >= 0) ----
  const int k = min(s_np * 3, Pn);
  unsigned prefix = 0, maskb = 0;
  int kk = k;
  int cntc = Pn;
  for (int shift = 24; shift >= 0; shift -= 8) {
    if (cntc <= 64) break;                         // small-select path below
    ((uint4*)hist)[tid] = make_uint4(0u, 0u, 0u, 0u);
    __syncthreads();
    #pragma unroll
    for (int sI = 0; sI < 9; sI++) {
      const int p = tid + 1024 * sI;
      if (p < Pn) {
        unsigned u = __float_as_uint(ce_r[sI]);
        if ((u & maskb) == prefix)
          atomicAdd(&hist[(((u >> shift) & 255u) << 4) + (unsigned)wave], 1u);
      }
    }
    __syncthreads();
    if (tid < 256) {
      unsigned c = 0;
      #pragma unroll
      for (int w = 0; w < 16; w++) c += hist[(tid << 4) + w];
      s_col[tid] = c;
    }
    __syncthreads();
    if (tid < 64) {
      // wave-0 parallel suffix scan over 256 bins (4 per lane)
      unsigned c0 = s_col[4 * tid + 0], c1 = s_col[4 * tid + 1];
      unsigned c2 = s_col[4 * tid + 2], c3 = s_col[4 * tid + 3];
      unsigned t0 = c0 + c1 + c2 + c3;
      unsigned S = t0;
      #pragma unroll
      for (int off = 1; off < 64; off <<= 1) {
        unsigned o = __shfl_down(S, off);
        if (tid + off < 64) S += o;
      }
      unsigned Snext = S - t0;                     // suffix of lanes > tid
      unsigned s3 = Snext + c3;
      unsigned s2 = s3 + c2;
      unsigned s1 = s2 + c1;
      unsigned s0 = s1 + c0;
      unsigned kk_u = (unsigned)kk;
      int chosen = -1; unsigned snx = 0, cc = 0;
      if (s3 >= kk_u && Snext < kk_u)      { chosen = 3; snx = Snext; cc = c3; }
      else if (s2 >= kk_u && s3 < kk_u)    { chosen = 2; snx = s3;    cc = c2; }
      else if (s1 >= kk_u && s2 < kk_u)    { chosen = 1; snx = s2;    cc = c1; }
      else if (s0 >= kk_u && s1 < kk_u)    { chosen = 0; snx = s1;    cc = c0; }
      if (chosen >= 0) {                           // exactly one lane hits
        s_prefix = prefix | ((unsigned)(4 * tid + chosen) << shift);
        s_kk = (int)(kk_u - snx);
        s_cnt = (int)cc;
      }
    }
    __syncthreads();
    prefix = s_prefix; kk = s_kk; cntc = s_cnt;
    maskb |= 255u << shift;
  }
  if (maskb != 0xFFFFFFFFu) {
    // <= 64 candidates share the prefix: exact rank-select in one wave
    if (tid == 0) s_cc = 0;
    __syncthreads();
    #pragma unroll
    for (int sI = 0; sI < 9; sI++) {
      const int p = tid + 1024 * sI;
      if (p < Pn) {
        unsigned u = __float_as_uint(ce_r[sI]);
        if ((u & maskb) == prefix) {
          int ix = atomicAdd(&s_cc, 1);
          if (ix < 64) s_cand[ix] = u;
        }
      }
    }
    __syncthreads();
    if (tid < 64) {
      int c = min(s_cc, 64);
      if (tid < c) {
        unsigned v = s_cand[tid];
        int g = 0, e = 0;
        for (int i = 0; i < c; i++) {
          unsigned w = s_cand[i];
          g += (w > v); e += (w == v);
        }
        if (g < kk && kk <= g + e) s_prefix = v;   // tie-safe: all writers equal
      }
    }
    __syncthreads();
    prefix = s_prefix;
  }
  float T = __uint_as_float(prefix);

  float sum_gt = 0.0f; int cnt_gt = 0;
  #pragma unroll
  for (int sI = 0; sI < 9; sI++) {
    const int p = tid + 1024 * sI;
    if (p < Pn) {
      float x = ce_r[sI];
      if (x > T) { sum_gt += x; cnt_gt++; }
    }
  }
  #pragma unroll
  for (int off = 32; off; off >>= 1) {
    sum_gt += __shfl_down(sum_gt, off);
    cnt_gt += __shfl_down(cnt_gt, off);
    my_loc += __shfl_down(my_loc, off);
    my_cep += __shfl_down(my_cep, off);
  }
  if (lane == 0) {
    s_redf[0][wave] = my_loc; s_redf[1][wave] = sum_gt + my_cep; s_redi[wave] = cnt_gt;
  }
  __syncthreads();
  if (tid == 0) {
    float ll = s_floc, lc = s_fcep; int cg2 = 0;
    #pragma unroll
    for (int w = 0; w < 16; w++) {
      ll += s_redf[0][w]; lc += s_redf[1][w]; cg2 += s_redi[w];
    }
    lc += (k > 0) ? (float)(k - cg2) * T : 0.0f;
    // post partials (device-scope atomics; visible cross-XCD), then flag
    atomicExch(&res[b * 4 + 0], __float_as_uint(ll));
    atomicExch(&res[b * 4 + 1], __float_as_uint(lc));
    atomicExch(&res[b * 4 + 2], (unsigned)s_np);
    __threadfence();
    atomicExch(&res[b * 4 + 3], MAGIC);
  }

  // block 0, wave 0: gather all 128 partials and finalize (no extra kernel)
  if (b == 0 && tid < 64) {
    float ll = 0.0f, lc = 0.0f; int np = 0;
    #pragma unroll
    for (int h = 0; h < 2; h++) {
      const int i = tid + 64 * h;
      while (atomicAdd(&res[i * 4 + 3], 0u) != MAGIC) { __builtin_amdgcn_s_sleep(8); }
      ll += __uint_as_float(atomicAdd(&res[i * 4 + 0], 0u));
      lc += __uint_as_float(atomicAdd(&res[i * 4 + 1], 0u));
      np += (int)atomicAdd(&res[i * 4 + 2], 0u);
    }
    #pragma unroll
    for (int off = 32; off; off >>= 1) {
      ll += __shfl_down(ll, off);
      lc += __shfl_down(lc, off);
      np += __shfl_down(np, off);
    }
    if (tid == 0) {
      float fN = (float)np;
      out[0] = ll / fN;
      out[1] = lc / fN;
    }
  }
}

extern "C" void kernel_launch(void* const* d_in, const int* in_sizes, int n_in,
                              void* d_out, int out_size, void* d_ws, size_t ws_size,
                              hipStream_t stream) {
  const float* loc_data  = (const float*)d_in[0];
  const float* conf_data = (const float*)d_in[1];
  const float* dbox      = (const float*)d_in[2];
  const float* targets   = (const float*)d_in[3];
  float* out = (float*)d_out;

  char* ws = (char*)d_ws;
  float* ce0 = (float*)ws;                                           // B*P f32
  unsigned char* pack = (unsigned char*)(ws + (size_t)Bn * Pn * 4);  // B*P bytes
  unsigned long long* keys =
      (unsigned long long*)(ws + (size_t)Bn * Pn * 5);               // B*16 u64
  unsigned int* res = (unsigned int*)(ws + (size_t)Bn * Pn * 5 + Bn * On * 8); // B*4 u32

  stream_kernel<<<1024, 256, 0, stream>>>(conf_data, dbox, targets, ce0, pack, keys);
  reduce_kernel<<<Bn, 1024, 0, stream>>>(loc_data, conf_data, dbox, targets,
                                         ce0, pack, keys, res, out);
}